// Round 3
// baseline (849.061 us; speedup 1.0000x reference)
//
#include <hip/hip_runtime.h>

#define BATCH 16
#define CIN   512
#define COUT  512
#define HDIM  64
#define HW    4096
#define STY   512
#define NTAP  9
// 1/sqrt(512*9)
#define SCALE 0.014731391274719739f

typedef __bf16 bf16x8 __attribute__((ext_vector_type(8)));
typedef float  f32x4  __attribute__((ext_vector_type(4)));

static __device__ __forceinline__ unsigned short f2bf(float f) {
  union { float f; unsigned u; } v; v.f = f;
  unsigned u = v.u;
  u += 0x7fffu + ((u >> 16) & 1u);   // RNE; inputs finite
  return (unsigned short)(u >> 16);
}

// S[b][ci] = SCALE * (sum_j style[b][j]*mod_w[ci][j] + mod_b[ci])
__global__ void k_style(const float* __restrict__ style, const float* __restrict__ mod_w,
                        const float* __restrict__ mod_b, float* __restrict__ S) {
  __shared__ __align__(16) float sty[STY];
  int b = blockIdx.x;
  for (int j = threadIdx.x; j < STY; j += 256) sty[j] = style[b*STY + j];
  __syncthreads();
  for (int ci = threadIdx.x; ci < CIN; ci += 256) {
    const float4* wr = reinterpret_cast<const float4*>(mod_w + ci*STY);
    const float4* sr = reinterpret_cast<const float4*>(sty);
    float acc = 0.f;
    #pragma unroll 4
    for (int j = 0; j < STY/4; ++j) {
      float4 w = wr[j], s = sr[j];
      acc += w.x*s.x + w.y*s.y + w.z*s.z + w.w*s.w;
    }
    S[b*CIN + ci] = SCALE * (acc + mod_b[ci]);
  }
}

// wsq[co][ci] = sum_tap weight^2 ; wpack[tap][co][ci] = bf16(weight) (tap-major, flat)
__global__ void k_wsq_pack(const float* __restrict__ weight, float* __restrict__ wsq,
                           unsigned short* __restrict__ wpack) {
  int co = blockIdx.x;
  for (int ci = threadIdx.x; ci < CIN; ci += 256) {
    const float* wp = weight + (co*CIN + ci)*NTAP;
    float ssq = 0.f;
    #pragma unroll
    for (int t = 0; t < NTAP; ++t) {
      float w = wp[t];
      ssq += w * w;
      wpack[(t*COUT + co)*CIN + ci] = f2bf(w);
    }
    wsq[co*CIN + ci] = ssq;
  }
}

// D[b][co] = rsqrt(sum_ci S^2 * wsq + eps); one wave per (b,co)
__global__ void k_demod(const float* __restrict__ S, const float* __restrict__ wsq,
                        float* __restrict__ D) {
  int wid  = blockIdx.x * 4 + (threadIdx.x >> 6);  // b*512 + co
  int lane = threadIdx.x & 63;
  int b  = wid >> 9;
  int co = wid & 511;
  float sum = 0.f;
  #pragma unroll
  for (int i = 0; i < CIN/64; ++i) {
    int ci = lane + i*64;
    float s = S[b*CIN + ci];
    sum += s * s * wsq[co*CIN + ci];
  }
  #pragma unroll
  for (int off = 32; off > 0; off >>= 1) sum += __shfl_down(sum, off);
  if (lane == 0) D[b*COUT + co] = rsqrtf(sum + 1e-8f);
}

// Main conv, A-in-registers structure:
//  - B halo staged in LDS per ci-chunk(32) (only LDS user: 21 KB -> high occupancy)
//  - A-fragments read straight from L2-resident wpack into a register double
//    buffer, prefetched one tap ahead (latency hides under previous tap's MFMAs)
//  - barriers per block: 32 (2 per chunk, Bs only); 144 MFMAs per barrier region
#define BPAD 40
#define TAPSTRIDE (COUT*CIN)   // elements per tap plane in wpack
__global__ __launch_bounds__(256) void k_conv(const float* __restrict__ in,
                                              const unsigned short* __restrict__ wpack,
                                              const float* __restrict__ S,
                                              const float* __restrict__ D,
                                              float* __restrict__ out) {
  const int b   = blockIdx.z;
  const int cog = blockIdx.y;
  const int co0 = cog * 128;
  const int pt  = blockIdx.x;
  const int h0  = pt * 2;

  const int tid  = threadIdx.x;
  const int lane = tid & 63;
  const int wave = tid >> 6;
  const int wm   = wave >> 1;       // co half of tile
  const int wn   = wave & 1;        // pixel half
  const int l15  = lane & 15;
  const int quad = lane >> 4;

  __shared__ __align__(16) unsigned short Bs[4 * 66 * BPAD];  // [halo row][halo col][ci]

  f32x4 zero = {0.f, 0.f, 0.f, 0.f};
  f32x4 acc[4][4];
  #pragma unroll
  for (int i = 0; i < 4; ++i)
    #pragma unroll
    for (int j = 0; j < 4; ++j) acc[i][j] = zero;

  const float* inb = in + b * (CIN * HW);

  // halo columns 0 and 65 (image w=-1,64) are always zero; write once
  if (tid < 32) {
    int row = tid >> 3, rem = tid & 7;
    int ch  = (rem >> 2) * 65;
    int ci8 = (rem & 3) * 8;
    uint4 z = {0u, 0u, 0u, 0u};
    *reinterpret_cast<uint4*>(&Bs[(row*66 + ch)*BPAD + ci8]) = z;
  }

  // A global read base (per mt): row = wm*64+mt*16+l15, 8 ci at quad*8.
  // 16 lanes x 4 quads cover full 64B lines of wpack -> coalesced dwordx4.
  const unsigned short* abase[4];
  #pragma unroll
  for (int mt = 0; mt < 4; ++mt) {
    int row = wm*64 + mt*16 + l15;
    abase[mt] = wpack + (size_t)(co0 + row)*CIN + quad*8;
  }

  int b_base[4];
  #pragma unroll
  for (int nt = 0; nt < 4; ++nt) {
    int px = wn*64 + nt*16 + l15;   // 0..127 within tile
    int r = px >> 6, c = px & 63;
    b_base[nt] = (r*66 + c) * BPAD + quad*8;  // + ((kh*66+kw)*BPAD) per tap
  }

  const int scol = tid & 63;   // image col this thread stages
  const int srow = tid >> 6;   // halo row (wave-uniform)

  auto stageB = [&](int ci0) {
    int g = h0 - 1 + srow;
    bool inr = (g >= 0) && (g < HDIM);
    const float* src = inb + ci0*HW + g*HDIM + scol;
    const float4* Sb4 = reinterpret_cast<const float4*>(S + b*CIN + ci0);
    #pragma unroll
    for (int cg = 0; cg < 4; ++cg) {
      float4 s0 = Sb4[cg*2];
      float4 s1 = Sb4[cg*2 + 1];
      float sv[8] = {s0.x, s0.y, s0.z, s0.w, s1.x, s1.y, s1.z, s1.w};
      unsigned short h[8];
      #pragma unroll
      for (int j = 0; j < 8; ++j) {
        float v = inr ? src[(cg*8 + j)*HW] : 0.f;
        h[j] = f2bf(v * sv[j]);
      }
      uint4 pk;
      pk.x = (unsigned)h[0] | ((unsigned)h[1] << 16);
      pk.y = (unsigned)h[2] | ((unsigned)h[3] << 16);
      pk.z = (unsigned)h[4] | ((unsigned)h[5] << 16);
      pk.w = (unsigned)h[6] | ((unsigned)h[7] << 16);
      *reinterpret_cast<uint4*>(&Bs[(srow*66 + scol + 1)*BPAD + cg*8]) = pk;
    }
  };

  // register double-buffer for A fragments; all indices compile-time (loops unrolled)
  uint4 A2[2][4];

  // prologue: prefetch A(tap0, chunk0); stage B(chunk0)
  #pragma unroll
  for (int mt = 0; mt < 4; ++mt)
    A2[0][mt] = *reinterpret_cast<const uint4*>(abase[mt]);
  stageB(0);
  __syncthreads();

  #pragma unroll 1
  for (int chunk = 0; chunk < 16; ++chunk) {
    #pragma unroll
    for (int t = 0; t < NTAP; ++t) {
      // prefetch next tap's A-fragments into the other reg buffer
      if (t < 8) {
        #pragma unroll
        for (int mt = 0; mt < 4; ++mt)
          A2[(t+1)&1][mt] = *reinterpret_cast<const uint4*>(
              abase[mt] + (t+1)*TAPSTRIDE + chunk*32);
      } else if (chunk < 15) {
        #pragma unroll
        for (int mt = 0; mt < 4; ++mt)
          A2[1][mt] = *reinterpret_cast<const uint4*>(
              abase[mt] + (chunk+1)*32);
      }
      const int toff = ((t/3)*66 + (t%3)) * BPAD;
      bf16x8 af[4], bfr[4];
      #pragma unroll
      for (int mt = 0; mt < 4; ++mt)
        af[mt] = __builtin_bit_cast(bf16x8, A2[t&1][mt]);
      #pragma unroll
      for (int nt = 0; nt < 4; ++nt) {
        uint4 raw = *reinterpret_cast<const uint4*>(&Bs[b_base[nt] + toff]);
        bfr[nt] = __builtin_bit_cast(bf16x8, raw);
      }
      __builtin_amdgcn_s_setprio(1);
      #pragma unroll
      for (int mt = 0; mt < 4; ++mt)
        #pragma unroll
        for (int nt = 0; nt < 4; ++nt)
          acc[mt][nt] = __builtin_amdgcn_mfma_f32_16x16x32_bf16(af[mt], bfr[nt], acc[mt][nt], 0, 0, 0);
      __builtin_amdgcn_s_setprio(0);
    }
    // fix tap-parity across chunk boundary: next chunk's tap0 was prefetched into A2[1]
    #pragma unroll
    for (int mt = 0; mt < 4; ++mt) A2[0][mt] = A2[1][mt];
    __syncthreads();              // all Bs reads of this chunk done
    if (chunk < 15) {
      stageB((chunk + 1) * 32);
      __syncthreads();            // Bs ready
    }
  }

  // epilogue: C/D layout col=lane&15 (pixel), row=quad*4+reg (co); apply demod here
  #pragma unroll
  for (int mt = 0; mt < 4; ++mt) {
    int co = co0 + wm*64 + mt*16 + quad*4;
    float dvr[4];
    #pragma unroll
    for (int r = 0; r < 4; ++r) dvr[r] = D[b*COUT + co + r];
    #pragma unroll
    for (int nt = 0; nt < 4; ++nt) {
      int px = pt*128 + wn*64 + nt*16 + l15;
      float* op = out + (b*COUT + co)*HW + px;
      #pragma unroll
      for (int r = 0; r < 4; ++r) op[r*HW] = acc[mt][nt][r] * dvr[r];
    }
  }
}

extern "C" void kernel_launch(void* const* d_in, const int* in_sizes, int n_in,
                              void* d_out, int out_size, void* d_ws, size_t ws_size,
                              hipStream_t stream) {
  const float* input  = (const float*)d_in[0];
  const float* style  = (const float*)d_in[1];
  const float* weight = (const float*)d_in[2];
  const float* mod_w  = (const float*)d_in[3];
  const float* mod_b  = (const float*)d_in[4];
  float* out = (float*)d_out;

  char* ws = (char*)d_ws;
  float* S = (float*)ws;                                   //    32 KB
  float* D = (float*)(ws + 32768);                         //    32 KB
  float* wsq = (float*)(ws + 65536);                       //     1 MB
  unsigned short* wpack = (unsigned short*)(ws + 65536 + 1048576);  // 4.72 MB (tap-major flat)
  // total ws need: 5,832,704 bytes

  k_style<<<BATCH, 256, 0, stream>>>(style, mod_w, mod_b, S);
  k_wsq_pack<<<COUT, 256, 0, stream>>>(weight, wsq, wpack);
  k_demod<<<(BATCH*COUT)/4, 256, 0, stream>>>(S, wsq, D);

  dim3 grid(HW/128, COUT/128, BATCH);
  k_conv<<<grid, 256, 0, stream>>>(input, wpack, S, D, out);
}

// Round 4
// 614.813 us; speedup vs baseline: 1.3810x; 1.3810x over previous
//
#include <hip/hip_runtime.h>

#define BATCH 16
#define CIN   512
#define COUT  512
#define HDIM  64
#define HW    4096
#define STY   512
#define NTAP  9
// 1/sqrt(512*9)
#define SCALE 0.014731391274719739f

typedef __bf16 bf16x8 __attribute__((ext_vector_type(8)));
typedef float  f32x4  __attribute__((ext_vector_type(4)));

static __device__ __forceinline__ unsigned short f2bf(float f) {
  union { float f; unsigned u; } v; v.f = f;
  unsigned u = v.u;
  u += 0x7fffu + ((u >> 16) & 1u);   // RNE; inputs finite
  return (unsigned short)(u >> 16);
}

typedef const __attribute__((address_space(1))) unsigned GBUF;
typedef __attribute__((address_space(3))) unsigned LBUF;
static __device__ __forceinline__ void gload_lds16(const void* g, void* l) {
  // async global->LDS DMA, 16B/lane; LDS dest = wave-uniform base + lane*16
  __builtin_amdgcn_global_load_lds((GBUF*)g, (LBUF*)l, 16, 0, 0);
}

// S[b][ci] = SCALE * (sum_j style[b][j]*mod_w[ci][j] + mod_b[ci])
__global__ void k_style(const float* __restrict__ style, const float* __restrict__ mod_w,
                        const float* __restrict__ mod_b, float* __restrict__ S) {
  __shared__ __align__(16) float sty[STY];
  int b = blockIdx.x;
  for (int j = threadIdx.x; j < STY; j += 256) sty[j] = style[b*STY + j];
  __syncthreads();
  for (int ci = threadIdx.x; ci < CIN; ci += 256) {
    const float4* wr = reinterpret_cast<const float4*>(mod_w + ci*STY);
    const float4* sr = reinterpret_cast<const float4*>(sty);
    float acc = 0.f;
    #pragma unroll 4
    for (int j = 0; j < STY/4; ++j) {
      float4 w = wr[j], s = sr[j];
      acc += w.x*s.x + w.y*s.y + w.z*s.z + w.w*s.w;
    }
    S[b*CIN + ci] = SCALE * (acc + mod_b[ci]);
  }
}

// xmod[b][h][w][ci] = bf16( input[b][ci][h][w] * S[b][ci] )  (ci innermost)
// LDS-transposed so both global read and global write are coalesced.
#define XP 65
__global__ void k_xmod(const float* __restrict__ in, const float* __restrict__ S,
                       unsigned short* __restrict__ xmod) {
  __shared__ unsigned short tile[64 * XP];
  int b   = blockIdx.z;
  int h   = blockIdx.y;
  int ci0 = blockIdx.x * 64;
  int w   = threadIdx.x & 63;
  int r4  = threadIdx.x >> 6;   // 0..3
  const float* src = in + (size_t)(b*CIN + ci0)*HW + h*HDIM + w;
  #pragma unroll
  for (int p = 0; p < 16; ++p) {
    int row = r4 + p*4;
    float s = S[b*CIN + ci0 + row];
    tile[row*XP + w] = f2bf(src[(size_t)row*HW] * s);
  }
  __syncthreads();
  int wo = threadIdx.x >> 2;          // 0..63
  int c0 = (threadIdx.x & 3) * 16;    // 0,16,32,48
  unsigned short hb[16];
  #pragma unroll
  for (int j = 0; j < 16; ++j) hb[j] = tile[(c0+j)*XP + wo];
  uint4 o0, o1;
  o0.x = (unsigned)hb[0]  | ((unsigned)hb[1]  << 16);
  o0.y = (unsigned)hb[2]  | ((unsigned)hb[3]  << 16);
  o0.z = (unsigned)hb[4]  | ((unsigned)hb[5]  << 16);
  o0.w = (unsigned)hb[6]  | ((unsigned)hb[7]  << 16);
  o1.x = (unsigned)hb[8]  | ((unsigned)hb[9]  << 16);
  o1.y = (unsigned)hb[10] | ((unsigned)hb[11] << 16);
  o1.z = (unsigned)hb[12] | ((unsigned)hb[13] << 16);
  o1.w = (unsigned)hb[14] | ((unsigned)hb[15] << 16);
  uint4* op = reinterpret_cast<uint4*>(xmod + (((size_t)(b*HDIM + h)*HDIM + wo)*CIN + ci0 + c0));
  op[0] = o0; op[1] = o1;
}

// wsq[co][ci] = sum_tap weight^2
// wpack: PRE-SWIZZLED bf16 weights for global_load_lds staging.
// Layout: [tap][cog(4)][chunk(16)][granule P(512)][8 bf16], granule content =
// w[cog*128+row][chunk*32 + q*8 .. +7], placed at P = row*4 + (q ^ ((row>>1)&3)).
// Same involution applied on the LDS read side in k_conv -> ~2-way banks.
__global__ void k_wsq_pack(const float* __restrict__ weight, float* __restrict__ wsq,
                           unsigned short* __restrict__ wpack) {
  int t  = threadIdx.x;
  int co = blockIdx.x*4 + (t >> 6);
  int g  = t & 63;            // ci granule (8 ci)
  int ci = g*8;
  const float* wp = weight + (co*CIN + ci)*NTAP;   // 72 consecutive floats
  float w[8][9];
  #pragma unroll
  for (int j = 0; j < 8; ++j)
    #pragma unroll
    for (int tp = 0; tp < 9; ++tp) w[j][tp] = wp[j*9 + tp];
  #pragma unroll
  for (int j = 0; j < 8; ++j) {
    float ssq = 0.f;
    #pragma unroll
    for (int tp = 0; tp < 9; ++tp) ssq += w[j][tp]*w[j][tp];
    wsq[co*CIN + ci + j] = ssq;
  }
  int row = co & 127, cog = co >> 7, chunk = g >> 2, q = g & 3;
  int P = row*4 + (q ^ ((row>>1)&3));
  #pragma unroll
  for (int tp = 0; tp < 9; ++tp) {
    unsigned short h[8];
    #pragma unroll
    for (int j = 0; j < 8; ++j) h[j] = f2bf(w[j][tp]);
    uint4 pk;
    pk.x = (unsigned)h[0] | ((unsigned)h[1] << 16);
    pk.y = (unsigned)h[2] | ((unsigned)h[3] << 16);
    pk.z = (unsigned)h[4] | ((unsigned)h[5] << 16);
    pk.w = (unsigned)h[6] | ((unsigned)h[7] << 16);
    int gran = ((tp*4 + cog)*16 + chunk)*512 + P;
    *reinterpret_cast<uint4*>(wpack + gran*8) = pk;
  }
}

// D[b][co] = rsqrt(sum_ci S^2 * wsq + eps); one wave per (b,co)
__global__ void k_demod(const float* __restrict__ S, const float* __restrict__ wsq,
                        float* __restrict__ D) {
  int wid  = blockIdx.x * 4 + (threadIdx.x >> 6);  // b*512 + co
  int lane = threadIdx.x & 63;
  int b  = wid >> 9;
  int co = wid & 511;
  float sum = 0.f;
  #pragma unroll
  for (int i = 0; i < CIN/64; ++i) {
    int ci = lane + i*64;
    float s = S[b*CIN + ci];
    sum += s * s * wsq[co*CIN + ci];
  }
  #pragma unroll
  for (int off = 32; off > 0; off >>= 1) sum += __shfl_down(sum, off);
  if (lane == 0) D[b*COUT + co] = rsqrtf(sum + 1e-8f);
}

// Main conv, round-4 structure:
//  - A: block-shared LDS, per-tap async DMA double-buffer (2x8KB), swizzled wpack
//  - B: pre-modulated bf16 xmod; 4 uint4 loads/thread/chunk issued at chunk start
//    (T14 early-issue), 4 ds_write_b128 at chunk end; Bs single-buffered
//  - LDS 37.2KB -> 4 blocks/CU by LDS; ~150 unified regs -> 3 blocks/CU resident
#define BPAD 40
__global__ __launch_bounds__(256) void k_conv(const unsigned short* __restrict__ xmod,
                                              const unsigned short* __restrict__ wpack,
                                              const float* __restrict__ D,
                                              float* __restrict__ out) {
  const int b   = blockIdx.z;
  const int cog = blockIdx.y;
  const int co0 = cog * 128;
  const int pt  = blockIdx.x;
  const int h0  = pt * 2;

  const int tid  = threadIdx.x;
  const int lane = tid & 63;
  const int wave = tid >> 6;
  const int wm   = wave >> 1;       // co half of tile
  const int wn   = wave & 1;        // pixel half
  const int l15  = lane & 15;
  const int quad = lane >> 4;

  __shared__ __align__(16) unsigned short As[2][4096];        // 2 x 8KB tap buffers (swz image)
  __shared__ __align__(16) unsigned short Bs[4 * 66 * BPAD];  // [halo row][halo col][ci]

  f32x4 zero = {0.f, 0.f, 0.f, 0.f};
  f32x4 acc[4][4];
  #pragma unroll
  for (int i = 0; i < 4; ++i)
    #pragma unroll
    for (int j = 0; j < 4; ++j) acc[i][j] = zero;

  // halo columns 0 and 65 (image w=-1,64) are always zero; write once
  if (tid < 32) {
    int row = tid >> 3, rem = tid & 7;
    int ch  = (rem >> 2) * 65;
    int ci8 = (rem & 3) * 8;
    uint4 z = {0u, 0u, 0u, 0u};
    *reinterpret_cast<uint4*>(&Bs[(row*66 + ch)*BPAD + ci8]) = z;
  }

  // A-frag offsets (elements within one 8KB tap block), swizzle-matched to wpack
  int pa_off[4], b_base[4];
  #pragma unroll
  for (int mt = 0; mt < 4; ++mt) {
    int row = wm*64 + mt*16 + l15;
    pa_off[mt] = (row*4 + (quad ^ ((row>>1)&3))) * 8;
  }
  #pragma unroll
  for (int nt = 0; nt < 4; ++nt) {
    int px = wn*64 + nt*16 + l15;   // 0..127 within tile
    int r = px >> 6, c = px & 63;
    b_base[nt] = (r*66 + c) * BPAD + quad*8;  // + ((kh*66+kw)*BPAD) per tap
  }

  // B staging map: row = tid>>6 (halo row, wave-uniform), per-it col/cg
  const int srow = tid >> 6;
  const int bcol = (lane >> 2);     // 0..15, +16 per it
  const int bcg  = lane & 3;        // ci 8-group
  const int g    = h0 - 1 + srow;
  const bool inr = (g >= 0) && (g < HDIM);
  const unsigned short* xsrc =
      xmod + ((size_t)(b*HDIM + (inr ? g : 0))*HDIM + bcol)*CIN + bcg*8;

  auto ldB = [&](int ci0, uint4* lB) {
    if (inr) {
      #pragma unroll
      for (int it = 0; it < 4; ++it)
        lB[it] = *reinterpret_cast<const uint4*>(xsrc + (size_t)(it*16)*CIN + ci0);
    } else {
      uint4 z = {0u,0u,0u,0u};
      #pragma unroll
      for (int it = 0; it < 4; ++it) lB[it] = z;
    }
  };
  auto wrB = [&](const uint4* lB) {
    #pragma unroll
    for (int it = 0; it < 4; ++it)
      *reinterpret_cast<uint4*>(&Bs[(srow*66 + bcol + it*16 + 1)*BPAD + bcg*8]) = lB[it];
  };

  // A staging: one tap = 8KB, 2 DMA instr per wave
  auto gllA = [&](int bufi, int tap, int chunk) {
    const char* gb = (const char*)wpack +
        ((size_t)(((tap*4 + cog)*16 + chunk) * 512) << 4);
    char* lb = (char*)&As[bufi][0];
    #pragma unroll
    for (int j = 0; j < 2; ++j) {
      int off = (wave*2 + j) * 1024;
      gload_lds16(gb + off + lane*16, lb + off);
    }
  };

  // --- prologue: A(tap0,chunk0) DMA; B(chunk0) load+write ---
  gllA(0, 0, 0);
  uint4 lB[4];
  ldB(0, lB);
  wrB(lB);
  __syncthreads();   // As[0]+Bs ready (barrier drains vmcnt+lgkm)

  int buf = 0;
  #pragma unroll 1
  for (int chunk = 0; chunk < 16; ++chunk) {
    if (chunk < 15) ldB((chunk + 1) * 32, lB);   // early-issue next chunk's B loads
    #pragma unroll
    for (int t = 0; t < NTAP; ++t) {
      // issue next tap's A DMA into the other buffer (its readers finished
      // before the barrier that ended the previous tap)
      if (t < 8)             gllA(buf^1, t+1, chunk);
      else if (chunk < 15)   gllA(buf^1, 0,   chunk+1);
      const int toff = ((t/3)*66 + (t%3)) * BPAD;
      bf16x8 af[4], bfr[4];
      #pragma unroll
      for (int mt = 0; mt < 4; ++mt) {
        uint4 raw = *reinterpret_cast<const uint4*>(&As[buf][pa_off[mt]]);
        af[mt] = __builtin_bit_cast(bf16x8, raw);
      }
      #pragma unroll
      for (int nt = 0; nt < 4; ++nt) {
        uint4 raw = *reinterpret_cast<const uint4*>(&Bs[b_base[nt] + toff]);
        bfr[nt] = __builtin_bit_cast(bf16x8, raw);
      }
      __builtin_amdgcn_s_setprio(1);
      #pragma unroll
      for (int mt = 0; mt < 4; ++mt)
        #pragma unroll
        for (int nt = 0; nt < 4; ++nt)
          acc[mt][nt] = __builtin_amdgcn_mfma_f32_16x16x32_bf16(af[mt], bfr[nt], acc[mt][nt], 0, 0, 0);
      __builtin_amdgcn_s_setprio(0);
      __syncthreads();   // As[buf] reads done; next-tap DMA drained
      buf ^= 1;
    }
    if (chunk < 15) {
      wrB(lB);           // all Bs reads of this chunk finished at last barrier
      __syncthreads();   // Bs ready
    }
  }

  // epilogue: C/D layout col=lane&15 (pixel), row=quad*4+reg (co); apply demod here
  #pragma unroll
  for (int mt = 0; mt < 4; ++mt) {
    int co = co0 + wm*64 + mt*16 + quad*4;
    float dvr[4];
    #pragma unroll
    for (int r = 0; r < 4; ++r) dvr[r] = D[b*COUT + co + r];
    #pragma unroll
    for (int nt = 0; nt < 4; ++nt) {
      int px = pt*128 + wn*64 + nt*16 + l15;
      float* op = out + ((size_t)(b*COUT + co))*HW + px;
      #pragma unroll
      for (int r = 0; r < 4; ++r) op[r*HW] = acc[mt][nt][r] * dvr[r];
    }
  }
}

extern "C" void kernel_launch(void* const* d_in, const int* in_sizes, int n_in,
                              void* d_out, int out_size, void* d_ws, size_t ws_size,
                              hipStream_t stream) {
  const float* input  = (const float*)d_in[0];
  const float* style  = (const float*)d_in[1];
  const float* weight = (const float*)d_in[2];
  const float* mod_w  = (const float*)d_in[3];
  const float* mod_b  = (const float*)d_in[4];
  float* out = (float*)d_out;

  char* ws = (char*)d_ws;
  float* S = (float*)ws;                                            //    32 KB
  float* D = (float*)(ws + 32768);                                  //    32 KB
  float* wsq = (float*)(ws + 65536);                                //     1 MB
  unsigned short* wpack = (unsigned short*)(ws + 1114112);          //  4.72 MB (swizzled)
  unsigned short* xmod  = (unsigned short*)(ws + 5832704);          // 67.1 MB
  // total ws need: 72,941,568 bytes

  k_style<<<BATCH, 256, 0, stream>>>(style, mod_w, mod_b, S);
  {
    dim3 g(CIN/64, HDIM, BATCH);
    k_xmod<<<g, 256, 0, stream>>>(input, S, xmod);
  }
  k_wsq_pack<<<COUT/4, 256, 0, stream>>>(weight, wsq, wpack);
  k_demod<<<(BATCH*COUT)/4, 256, 0, stream>>>(S, wsq, D);

  dim3 grid(HW/128, COUT/128, BATCH);
  k_conv<<<grid, 256, 0, stream>>>(xmod, wpack, D, out);
}

// Round 5
// 546.997 us; speedup vs baseline: 1.5522x; 1.1240x over previous
//
#include <hip/hip_runtime.h>

#define BATCH 16
#define CIN   512
#define COUT  512
#define HDIM  64
#define HW    4096
#define STY   512
#define NTAP  9
// 1/sqrt(512*9)
#define SCALE 0.014731391274719739f

typedef __bf16 bf16x8 __attribute__((ext_vector_type(8)));
typedef float  f32x4  __attribute__((ext_vector_type(4)));

static __device__ __forceinline__ unsigned short f2bf(float f) {
  union { float f; unsigned u; } v; v.f = f;
  unsigned u = v.u;
  u += 0x7fffu + ((u >> 16) & 1u);   // RNE; inputs finite
  return (unsigned short)(u >> 16);
}

typedef const __attribute__((address_space(1))) unsigned GBUF;
typedef __attribute__((address_space(3))) unsigned LBUF;
static __device__ __forceinline__ void gload_lds16(const void* g, void* l) {
  // async global->LDS DMA, 16B/lane; LDS dest = wave-uniform base + lane*16
  __builtin_amdgcn_global_load_lds((GBUF*)g, (LBUF*)l, 16, 0, 0);
}

// raw barrier with compiler memory fences on both sides (no waitcnt drain)
#define BARRIER() do { asm volatile("" ::: "memory"); \
                       __builtin_amdgcn_s_barrier();  \
                       asm volatile("" ::: "memory"); } while (0)

// S[b][ci] = SCALE * (sum_j style[b][j]*mod_w[ci][j] + mod_b[ci])
__global__ void k_style(const float* __restrict__ style, const float* __restrict__ mod_w,
                        const float* __restrict__ mod_b, float* __restrict__ S) {
  __shared__ __align__(16) float sty[STY];
  int b = blockIdx.x;
  for (int j = threadIdx.x; j < STY; j += 256) sty[j] = style[b*STY + j];
  __syncthreads();
  for (int ci = threadIdx.x; ci < CIN; ci += 256) {
    const float4* wr = reinterpret_cast<const float4*>(mod_w + ci*STY);
    const float4* sr = reinterpret_cast<const float4*>(sty);
    float acc = 0.f;
    #pragma unroll 4
    for (int j = 0; j < STY/4; ++j) {
      float4 w = wr[j], s = sr[j];
      acc += w.x*s.x + w.y*s.y + w.z*s.z + w.w*s.w;
    }
    S[b*CIN + ci] = SCALE * (acc + mod_b[ci]);
  }
}

// xmod[b][h][w][ci] = bf16( input[b][ci][h][w] * S[b][ci] )  (ci innermost)
// LDS-transposed so both global read and global write are coalesced.
#define XP 65
__global__ void k_xmod(const float* __restrict__ in, const float* __restrict__ S,
                       unsigned short* __restrict__ xmod) {
  __shared__ unsigned short tile[64 * XP];
  int b   = blockIdx.z;
  int h   = blockIdx.y;
  int ci0 = blockIdx.x * 64;
  int w   = threadIdx.x & 63;
  int r4  = threadIdx.x >> 6;   // 0..3
  const float* src = in + (size_t)(b*CIN + ci0)*HW + h*HDIM + w;
  #pragma unroll
  for (int p = 0; p < 16; ++p) {
    int row = r4 + p*4;
    float s = S[b*CIN + ci0 + row];
    tile[row*XP + w] = f2bf(src[(size_t)row*HW] * s);
  }
  __syncthreads();
  int wo = threadIdx.x >> 2;          // 0..63
  int c0 = (threadIdx.x & 3) * 16;    // 0,16,32,48
  unsigned short hb[16];
  #pragma unroll
  for (int j = 0; j < 16; ++j) hb[j] = tile[(c0+j)*XP + wo];
  uint4 o0, o1;
  o0.x = (unsigned)hb[0]  | ((unsigned)hb[1]  << 16);
  o0.y = (unsigned)hb[2]  | ((unsigned)hb[3]  << 16);
  o0.z = (unsigned)hb[4]  | ((unsigned)hb[5]  << 16);
  o0.w = (unsigned)hb[6]  | ((unsigned)hb[7]  << 16);
  o1.x = (unsigned)hb[8]  | ((unsigned)hb[9]  << 16);
  o1.y = (unsigned)hb[10] | ((unsigned)hb[11] << 16);
  o1.z = (unsigned)hb[12] | ((unsigned)hb[13] << 16);
  o1.w = (unsigned)hb[14] | ((unsigned)hb[15] << 16);
  uint4* op = reinterpret_cast<uint4*>(xmod + (((size_t)(b*HDIM + h)*HDIM + wo)*CIN + ci0 + c0));
  op[0] = o0; op[1] = o1;
}

// wsq[co][ci] = sum_tap weight^2
// wpack: PRE-SWIZZLED bf16 weights for global_load_lds staging.
// Layout: [tap][cog(4)][chunk(16)][granule P(512)][8 bf16], granule content =
// w[cog*128+row][chunk*32 + q*8 .. +7], placed at P = row*4 + (q ^ ((row>>1)&3)).
// Same involution applied on the LDS read side in k_conv -> ~2-way banks.
__global__ void k_wsq_pack(const float* __restrict__ weight, float* __restrict__ wsq,
                           unsigned short* __restrict__ wpack) {
  int t  = threadIdx.x;
  int co = blockIdx.x*4 + (t >> 6);
  int g  = t & 63;            // ci granule (8 ci)
  int ci = g*8;
  const float* wp = weight + (co*CIN + ci)*NTAP;   // 72 consecutive floats
  float w[8][9];
  #pragma unroll
  for (int j = 0; j < 8; ++j)
    #pragma unroll
    for (int tp = 0; tp < 9; ++tp) w[j][tp] = wp[j*9 + tp];
  #pragma unroll
  for (int j = 0; j < 8; ++j) {
    float ssq = 0.f;
    #pragma unroll
    for (int tp = 0; tp < 9; ++tp) ssq += w[j][tp]*w[j][tp];
    wsq[co*CIN + ci + j] = ssq;
  }
  int row = co & 127, cog = co >> 7, chunk = g >> 2, q = g & 3;
  int P = row*4 + (q ^ ((row>>1)&3));
  #pragma unroll
  for (int tp = 0; tp < 9; ++tp) {
    unsigned short h[8];
    #pragma unroll
    for (int j = 0; j < 8; ++j) h[j] = f2bf(w[j][tp]);
    uint4 pk;
    pk.x = (unsigned)h[0] | ((unsigned)h[1] << 16);
    pk.y = (unsigned)h[2] | ((unsigned)h[3] << 16);
    pk.z = (unsigned)h[4] | ((unsigned)h[5] << 16);
    pk.w = (unsigned)h[6] | ((unsigned)h[7] << 16);
    int gran = ((tp*4 + cog)*16 + chunk)*512 + P;
    *reinterpret_cast<uint4*>(wpack + gran*8) = pk;
  }
}

// D[b][co] = rsqrt(sum_ci S^2 * wsq + eps); one wave per (b,co)
__global__ void k_demod(const float* __restrict__ S, const float* __restrict__ wsq,
                        float* __restrict__ D) {
  int wid  = blockIdx.x * 4 + (threadIdx.x >> 6);  // b*512 + co
  int lane = threadIdx.x & 63;
  int b  = wid >> 9;
  int co = wid & 511;
  float sum = 0.f;
  #pragma unroll
  for (int i = 0; i < CIN/64; ++i) {
    int ci = lane + i*64;
    float s = S[b*CIN + ci];
    sum += s * s * wsq[co*CIN + ci];
  }
  #pragma unroll
  for (int off = 32; off > 0; off >>= 1) sum += __shfl_down(sum, off);
  if (lane == 0) D[b*COUT + co] = rsqrtf(sum + 1e-8f);
}

// Main conv, round-5 structure (T3+T4):
//  - A: ring of 3 tap-buffers (3x8KB), async DMA prefetch depth 2, COUNTED
//    s_waitcnt vmcnt(N) + raw s_barrier per tap (never vmcnt(0) in the loop)
//  - B: pre-modulated xmod, reg-staged once per ci-chunk (as r4)
//  vmcnt accounting (per wave, per tap t): outstanding at wait =
//    [ldB(4) if t<2 and issued this chunk] + DMA(t)(2) + DMA(t+1)(2)
//    -> wait 6 (t<2, chunk<15), else 2; chunk15 tail: t<2 ->2, t==8 ->0.
#define BPAD 40
__global__ __launch_bounds__(256, 3) void k_conv(const unsigned short* __restrict__ xmod,
                                                 const unsigned short* __restrict__ wpack,
                                                 const float* __restrict__ D,
                                                 float* __restrict__ out) {
  const int b   = blockIdx.z;
  const int cog = blockIdx.y;
  const int co0 = cog * 128;
  const int pt  = blockIdx.x;
  const int h0  = pt * 2;

  const int tid  = threadIdx.x;
  const int lane = tid & 63;
  const int wave = tid >> 6;
  const int wm   = wave >> 1;       // co half of tile
  const int wn   = wave & 1;        // pixel half
  const int l15  = lane & 15;
  const int quad = lane >> 4;

  __shared__ __align__(16) unsigned short As[3][4096];        // ring of 3 x 8KB tap buffers
  __shared__ __align__(16) unsigned short Bs[4 * 66 * BPAD];  // [halo row][halo col][ci]

  f32x4 zero = {0.f, 0.f, 0.f, 0.f};
  f32x4 acc[4][4];
  #pragma unroll
  for (int i = 0; i < 4; ++i)
    #pragma unroll
    for (int j = 0; j < 4; ++j) acc[i][j] = zero;

  // halo columns 0 and 65 (image w=-1,64) are always zero; write once
  if (tid < 32) {
    int row = tid >> 3, rem = tid & 7;
    int ch  = (rem >> 2) * 65;
    int ci8 = (rem & 3) * 8;
    uint4 z = {0u, 0u, 0u, 0u};
    *reinterpret_cast<uint4*>(&Bs[(row*66 + ch)*BPAD + ci8]) = z;
  }

  // A-frag offsets (elements within one 8KB tap block), swizzle-matched to wpack
  int pa_off[4], b_base[4];
  #pragma unroll
  for (int mt = 0; mt < 4; ++mt) {
    int row = wm*64 + mt*16 + l15;
    pa_off[mt] = (row*4 + (quad ^ ((row>>1)&3))) * 8;
  }
  #pragma unroll
  for (int nt = 0; nt < 4; ++nt) {
    int px = wn*64 + nt*16 + l15;   // 0..127 within tile
    int r = px >> 6, c = px & 63;
    b_base[nt] = (r*66 + c) * BPAD + quad*8;  // + ((kh*66+kw)*BPAD) per tap
  }

  // B staging map: row = tid>>6 (halo row, wave-uniform), per-it col/cg
  const int srow = tid >> 6;
  const int bcol = (lane >> 2);     // 0..15, +16 per it
  const int bcg  = lane & 3;        // ci 8-group
  const int g    = h0 - 1 + srow;
  const bool inr = (g >= 0) && (g < HDIM);
  const unsigned short* xsrc =
      xmod + ((size_t)(b*HDIM + (inr ? g : 0))*HDIM + bcol)*CIN + bcg*8;

  auto ldB = [&](int ci0, uint4* lB) {
    if (inr) {
      #pragma unroll
      for (int it = 0; it < 4; ++it)
        lB[it] = *reinterpret_cast<const uint4*>(xsrc + (size_t)(it*16)*CIN + ci0);
    } else {
      uint4 z = {0u,0u,0u,0u};
      #pragma unroll
      for (int it = 0; it < 4; ++it) lB[it] = z;
    }
  };
  auto wrB = [&](const uint4* lB) {
    #pragma unroll
    for (int it = 0; it < 4; ++it)
      *reinterpret_cast<uint4*>(&Bs[(srow*66 + bcol + it*16 + 1)*BPAD + bcg*8]) = lB[it];
  };

  // A staging: one tap = 8KB, 2 DMA instr per wave (= 2 vmcnt units)
  auto gllA = [&](int bufi, int tap, int chunk) {
    const char* gb = (const char*)wpack +
        ((size_t)(((tap*4 + cog)*16 + chunk) * 512) << 4);
    char* lb = (char*)&As[bufi][0];
    #pragma unroll
    for (int j = 0; j < 2; ++j) {
      int off = (wave*2 + j) * 1024;
      gload_lds16(gb + off + lane*16, lb + off);
    }
  };

  // --- prologue ---
  uint4 lB[4];
  ldB(0, lB);          // 4 vm ops (oldest)
  gllA(0, 0, 0);       // DMA tap0 -> buf0 (2)
  gllA(1, 1, 0);       // DMA tap1 -> buf1 (2)
  asm volatile("s_waitcnt vmcnt(4)" ::: "memory");  // B done; tap0/1 in flight
  wrB(lB);
  asm volatile("s_waitcnt lgkmcnt(0)" ::: "memory");
  BARRIER();           // Bs + zero-halo ready

  #pragma unroll 1
  for (int chunk = 0; chunk < 16; ++chunk) {
    if (chunk < 15) ldB((chunk + 1) * 32, lB);   // early-issue next chunk's B (4 vm)
    #pragma unroll
    for (int t = 0; t < NTAP; ++t) {
      // counted wait: guarantee DMA(tap t) landed, keep newer DMAs in flight
      if (t < 2) {
        if (chunk < 15) asm volatile("s_waitcnt vmcnt(6)" ::: "memory");
        else            asm volatile("s_waitcnt vmcnt(2)" ::: "memory");
      } else if (t == 8) {
        if (chunk < 15) asm volatile("s_waitcnt vmcnt(2)" ::: "memory");
        else            asm volatile("s_waitcnt vmcnt(0)" ::: "memory");
      } else {
        asm volatile("s_waitcnt vmcnt(2)" ::: "memory");
      }
      BARRIER();   // all waves' DMA(t) landed; all readers of buf[(t+2)%3] done
      // issue DMA 2 taps ahead into the ring slot just freed
      if (t < 7)             gllA((t+2)%3, t+2, chunk);
      else if (chunk < 15)   gllA((t+2)%3, t-7, chunk+1);
      const int toff = ((t/3)*66 + (t%3)) * BPAD;
      bf16x8 af[4], bfr[4];
      #pragma unroll
      for (int mt = 0; mt < 4; ++mt) {
        uint4 raw = *reinterpret_cast<const uint4*>(&As[t%3][pa_off[mt]]);
        af[mt] = __builtin_bit_cast(bf16x8, raw);
      }
      #pragma unroll
      for (int nt = 0; nt < 4; ++nt) {
        uint4 raw = *reinterpret_cast<const uint4*>(&Bs[b_base[nt] + toff]);
        bfr[nt] = __builtin_bit_cast(bf16x8, raw);
      }
      __builtin_amdgcn_s_setprio(1);
      #pragma unroll
      for (int mt = 0; mt < 4; ++mt)
        #pragma unroll
        for (int nt = 0; nt < 4; ++nt)
          acc[mt][nt] = __builtin_amdgcn_mfma_f32_16x16x32_bf16(af[mt], bfr[nt], acc[mt][nt], 0, 0, 0);
      __builtin_amdgcn_s_setprio(0);
    }
    // chunk boundary: swap Bs without draining vmcnt (next-chunk DMAs in flight)
    if (chunk < 15) {
      BARRIER();         // all waves' Bs reads of this chunk consumed
      wrB(lB);
      asm volatile("s_waitcnt lgkmcnt(0)" ::: "memory");
      BARRIER();         // Bs ready
    }
  }

  // epilogue: C/D layout col=lane&15 (pixel), row=quad*4+reg (co); apply demod here
  #pragma unroll
  for (int mt = 0; mt < 4; ++mt) {
    int co = co0 + wm*64 + mt*16 + quad*4;
    float dvr[4];
    #pragma unroll
    for (int r = 0; r < 4; ++r) dvr[r] = D[b*COUT + co + r];
    #pragma unroll
    for (int nt = 0; nt < 4; ++nt) {
      int px = pt*128 + wn*64 + nt*16 + l15;
      float* op = out + ((size_t)(b*COUT + co))*HW + px;
      #pragma unroll
      for (int r = 0; r < 4; ++r) op[r*HW] = acc[mt][nt][r] * dvr[r];
    }
  }
}

extern "C" void kernel_launch(void* const* d_in, const int* in_sizes, int n_in,
                              void* d_out, int out_size, void* d_ws, size_t ws_size,
                              hipStream_t stream) {
  const float* input  = (const float*)d_in[0];
  const float* style  = (const float*)d_in[1];
  const float* weight = (const float*)d_in[2];
  const float* mod_w  = (const float*)d_in[3];
  const float* mod_b  = (const float*)d_in[4];
  float* out = (float*)d_out;

  char* ws = (char*)d_ws;
  float* S = (float*)ws;                                            //    32 KB
  float* D = (float*)(ws + 32768);                                  //    32 KB
  float* wsq = (float*)(ws + 65536);                                //     1 MB
  unsigned short* wpack = (unsigned short*)(ws + 1114112);          //  4.72 MB (swizzled)
  unsigned short* xmod  = (unsigned short*)(ws + 5832704);          // 67.1 MB
  // total ws need: 72,941,568 bytes

  k_style<<<BATCH, 256, 0, stream>>>(style, mod_w, mod_b, S);
  {
    dim3 g(CIN/64, HDIM, BATCH);
    k_xmod<<<g, 256, 0, stream>>>(input, S, xmod);
  }
  k_wsq_pack<<<COUT/4, 256, 0, stream>>>(weight, wsq, wpack);
  k_demod<<<(BATCH*COUT)/4, 256, 0, stream>>>(S, wsq, D);

  dim3 grid(HW/128, COUT/128, BATCH);
  k_conv<<<grid, 256, 0, stream>>>(xmod, wpack, D, out);
}

// Round 6
// 513.806 us; speedup vs baseline: 1.6525x; 1.0646x over previous
//
#include <hip/hip_runtime.h>

#define BATCH 16
#define CIN   512
#define COUT  512
#define HDIM  64
#define HW    4096
#define STY   512
#define NTAP  9
// 1/sqrt(512*9)
#define SCALE 0.014731391274719739f

typedef __bf16 bf16x8 __attribute__((ext_vector_type(8)));
typedef float  f32x4  __attribute__((ext_vector_type(4)));

static __device__ __forceinline__ unsigned short f2bf(float f) {
  union { float f; unsigned u; } v; v.f = f;
  unsigned u = v.u;
  u += 0x7fffu + ((u >> 16) & 1u);   // RNE; inputs finite
  return (unsigned short)(u >> 16);
}

typedef const __attribute__((address_space(1))) unsigned GBUF;
typedef __attribute__((address_space(3))) unsigned LBUF;
static __device__ __forceinline__ void gload_lds16(const void* g, void* l) {
  // async global->LDS DMA, 16B/lane; LDS dest = wave-uniform base + lane*16
  __builtin_amdgcn_global_load_lds((GBUF*)g, (LBUF*)l, 16, 0, 0);
}

// S[b][ci] = SCALE * (sum_j style[b][j]*mod_w[ci][j] + mod_b[ci])
__global__ void k_style(const float* __restrict__ style, const float* __restrict__ mod_w,
                        const float* __restrict__ mod_b, float* __restrict__ S) {
  __shared__ __align__(16) float sty[STY];
  int b = blockIdx.x;
  for (int j = threadIdx.x; j < STY; j += 256) sty[j] = style[b*STY + j];
  __syncthreads();
  for (int ci = threadIdx.x; ci < CIN; ci += 256) {
    const float4* wr = reinterpret_cast<const float4*>(mod_w + ci*STY);
    const float4* sr = reinterpret_cast<const float4*>(sty);
    float acc = 0.f;
    #pragma unroll 4
    for (int j = 0; j < STY/4; ++j) {
      float4 w = wr[j], s = sr[j];
      acc += w.x*s.x + w.y*s.y + w.z*s.z + w.w*s.w;
    }
    S[b*CIN + ci] = SCALE * (acc + mod_b[ci]);
  }
}

// xmod[b][h][w][ci] = bf16( input[b][ci][h][w] * S[b][ci] )  (ci innermost)
#define XP 65
__global__ void k_xmod(const float* __restrict__ in, const float* __restrict__ S,
                       unsigned short* __restrict__ xmod) {
  __shared__ unsigned short tile[64 * XP];
  int b   = blockIdx.z;
  int h   = blockIdx.y;
  int ci0 = blockIdx.x * 64;
  int w   = threadIdx.x & 63;
  int r4  = threadIdx.x >> 6;   // 0..3
  const float* src = in + (size_t)(b*CIN + ci0)*HW + h*HDIM + w;
  #pragma unroll
  for (int p = 0; p < 16; ++p) {
    int row = r4 + p*4;
    float s = S[b*CIN + ci0 + row];
    tile[row*XP + w] = f2bf(src[(size_t)row*HW] * s);
  }
  __syncthreads();
  int wo = threadIdx.x >> 2;          // 0..63
  int c0 = (threadIdx.x & 3) * 16;    // 0,16,32,48
  unsigned short hb[16];
  #pragma unroll
  for (int j = 0; j < 16; ++j) hb[j] = tile[(c0+j)*XP + wo];
  uint4 o0, o1;
  o0.x = (unsigned)hb[0]  | ((unsigned)hb[1]  << 16);
  o0.y = (unsigned)hb[2]  | ((unsigned)hb[3]  << 16);
  o0.z = (unsigned)hb[4]  | ((unsigned)hb[5]  << 16);
  o0.w = (unsigned)hb[6]  | ((unsigned)hb[7]  << 16);
  o1.x = (unsigned)hb[8]  | ((unsigned)hb[9]  << 16);
  o1.y = (unsigned)hb[10] | ((unsigned)hb[11] << 16);
  o1.z = (unsigned)hb[12] | ((unsigned)hb[13] << 16);
  o1.w = (unsigned)hb[14] | ((unsigned)hb[15] << 16);
  uint4* op = reinterpret_cast<uint4*>(xmod + (((size_t)(b*HDIM + h)*HDIM + wo)*CIN + ci0 + c0));
  op[0] = o0; op[1] = o1;
}

// wsq[co][ci] = sum_tap weight^2 ; wpack pre-swizzled (granule P = row*4 + (q ^ ((row>>1)&3)))
// block 0 additionally zeroes the 4-KB zbuf used by k_conv's OOB-row B-DMA.
__global__ void k_wsq_pack(const float* __restrict__ weight, float* __restrict__ wsq,
                           unsigned short* __restrict__ wpack, uint4* __restrict__ zbuf) {
  if (blockIdx.x == 0) {
    uint4 z = {0u,0u,0u,0u};
    zbuf[threadIdx.x] = z;          // 256 * 16B = 4 KB
  }
  int t  = threadIdx.x;
  int co = blockIdx.x*4 + (t >> 6);
  int g  = t & 63;            // ci granule (8 ci)
  int ci = g*8;
  const float* wp = weight + (co*CIN + ci)*NTAP;   // 72 consecutive floats
  float w[8][9];
  #pragma unroll
  for (int j = 0; j < 8; ++j)
    #pragma unroll
    for (int tp = 0; tp < 9; ++tp) w[j][tp] = wp[j*9 + tp];
  #pragma unroll
  for (int j = 0; j < 8; ++j) {
    float ssq = 0.f;
    #pragma unroll
    for (int tp = 0; tp < 9; ++tp) ssq += w[j][tp]*w[j][tp];
    wsq[co*CIN + ci + j] = ssq;
  }
  int row = co & 127, cog = co >> 7, chunk = g >> 2, q = g & 3;
  int P = row*4 + (q ^ ((row>>1)&3));
  #pragma unroll
  for (int tp = 0; tp < 9; ++tp) {
    unsigned short h[8];
    #pragma unroll
    for (int j = 0; j < 8; ++j) h[j] = f2bf(w[j][tp]);
    uint4 pk;
    pk.x = (unsigned)h[0] | ((unsigned)h[1] << 16);
    pk.y = (unsigned)h[2] | ((unsigned)h[3] << 16);
    pk.z = (unsigned)h[4] | ((unsigned)h[5] << 16);
    pk.w = (unsigned)h[6] | ((unsigned)h[7] << 16);
    int gran = ((tp*4 + cog)*16 + chunk)*512 + P;
    *reinterpret_cast<uint4*>(wpack + gran*8) = pk;
  }
}

// D[b][co] = rsqrt(sum_ci S^2 * wsq + eps); one wave per (b,co)
__global__ void k_demod(const float* __restrict__ S, const float* __restrict__ wsq,
                        float* __restrict__ D) {
  int wid  = blockIdx.x * 4 + (threadIdx.x >> 6);  // b*512 + co
  int lane = threadIdx.x & 63;
  int b  = wid >> 9;
  int co = wid & 511;
  float sum = 0.f;
  #pragma unroll
  for (int i = 0; i < CIN/64; ++i) {
    int ci = lane + i*64;
    float s = S[b*CIN + ci];
    sum += s * s * wsq[co*CIN + ci];
  }
  #pragma unroll
  for (int off = 32; off > 0; off >>= 1) sum += __shfl_down(sum, off);
  if (lane == 0) D[b*COUT + co] = rsqrtf(sum + 1e-8f);
}

// Main conv, round-6 structure:
//  - A: ring-3 x 8KB slots via DMA (as r5), counted vmcnt
//  - B: also via DMA from pre-modulated xmod, ring-6 x 4KB hrow-planes,
//    granule+XOR layout P = col*4 + (quad^(col&3)) -> conflict-free reads.
//    Plane DMAs for chunk c+1 at taps 0(l0,l1)/3(l2)/6(l3) of chunk c.
//  - image-edge cols masked per-lane; OOB rows DMA'd from 4-KB zero scratch
//  - 1 barrier/tap, no chunk-boundary barriers; tail chunk peeled for literal waits
//  vmcnt (per wave, derived from op timeline): steady [2,4,4,2,3,3,2,3,3];
//  tail [2,2,2,2,2,2,2,2,0].
__global__ __launch_bounds__(256, 3) void k_conv(const unsigned short* __restrict__ xmod,
                                                 const unsigned short* __restrict__ wpack,
                                                 const float* __restrict__ D,
                                                 const char* __restrict__ zbuf,
                                                 float* __restrict__ out) {
  const int b   = blockIdx.z;
  const int cog = blockIdx.y;
  const int co0 = cog * 128;
  const int pt  = blockIdx.x;
  const int h0  = pt * 2;

  const int tid  = threadIdx.x;
  const int lane = tid & 63;
  const int wave = tid >> 6;
  const int wm   = wave >> 1;       // co half of tile
  const int wn   = wave & 1;        // pixel row (image row h0+wn)
  const int l15  = lane & 15;
  const int quad = lane >> 4;

  // [0, 24576): B ring-6 planes (6 x 4KB); [24576, 49152): A ring-3 slots (3 x 8KB)
  __shared__ __align__(16) char ldsb[49152];

  f32x4 zero = {0.f, 0.f, 0.f, 0.f};
  f32x4 acc[4][4];
  #pragma unroll
  for (int i = 0; i < 4; ++i)
    #pragma unroll
    for (int j = 0; j < 4; ++j) acc[i][j] = zero;

  // A-frag byte offsets within an 8KB slot (swizzle-matched to wpack)
  int pa_off[4];
  #pragma unroll
  for (int mt = 0; mt < 4; ++mt) {
    int row = wm*64 + mt*16 + l15;
    pa_off[mt] = (row*4 + (quad ^ ((row>>1)&3))) * 16;
  }

  // B-frag byte offsets within a 4KB plane, per kw (col = nt*16 + l15 + kw - 1;
  // the nt term is the +nt*1024 immediate). colr=-1 / 64 are edge-masked.
  int b_off[3];
  #pragma unroll
  for (int kw = 0; kw < 3; ++kw) {
    int colr = l15 + kw - 1;            // -1..16
    b_off[kw] = colr*64 + ((quad ^ (colr & 3)) << 4);
  }
  const bool m0  = (l15 == 0);
  const bool m63 = (l15 == 15);
  const bf16x8 z8 = __builtin_bit_cast(bf16x8, (uint4){0u,0u,0u,0u});

  // B-DMA per-lane global sources, one per logical plane (row h0-1+l)
  const int colw = wave*16 + (lane >> 2);
  const int qeff = (lane & 3) ^ ((lane >> 2) & 3);
  const char* xb = (const char*)xmod;
  const char* pB0; const char* pB1; const char* pB2; const char* pB3;
  {
    int gr;
    gr = h0 - 1;  pB0 = (gr >= 0 && gr < HDIM) ? xb + (size_t)(b*HDIM + gr)*65536 + colw*1024 + qeff*16
                                               : zbuf + lane*16;
    gr = h0;      pB1 = xb + (size_t)(b*HDIM + gr)*65536 + colw*1024 + qeff*16;
    gr = h0 + 1;  pB2 = xb + (size_t)(b*HDIM + gr)*65536 + colw*1024 + qeff*16;
    gr = h0 + 2;  pB3 = (gr < HDIM) ? xb + (size_t)(b*HDIM + gr)*65536 + colw*1024 + qeff*16
                                    : zbuf + lane*16;
  }

  auto gllA = [&](int s, int tap, int chunk) {
    const char* gb = (const char*)wpack + (size_t)(((tap*4 + cog)*16 + chunk)) * 8192;
    char* lb = ldsb + 24576 + s*8192;
    gload_lds16(gb + (wave*2 + 0)*1024 + lane*16, lb + (wave*2 + 0)*1024);
    gload_lds16(gb + (wave*2 + 1)*1024 + lane*16, lb + (wave*2 + 1)*1024);
  };

// B plane DMA: logical plane L of next chunk -> phys slot (w6+L) mod 6
#define GLB(L) do {                                                            \
    int pw_ = w6 + (L); if (pw_ >= 6) pw_ -= 6;                                \
    gload_lds16(pB##L, ldsb + (pw_ << 12) + wave*1024);                        \
  } while (0)

// One tap: counted wait (literal), barrier, prefetch issues, frag reads, 16 MFMA.
#define TAP(T, VC, STEADY)                                                     \
  {                                                                            \
    asm volatile("s_waitcnt vmcnt(" #VC ")" ::: "memory");                     \
    __builtin_amdgcn_s_barrier();                                              \
    asm volatile("" ::: "memory");                                             \
    if (STEADY) {                                                              \
      if ((T) < 7) gllA(((T)+2)%3, (T)+2, chunk);                              \
      else         gllA(((T)+2)%3, (T)-7, chunk+1);                            \
      if ((T) == 0) { GLB(0); GLB(1); }                                        \
      if ((T) == 3) { GLB(2); }                                                \
      if ((T) == 6) { GLB(3); }                                                \
    } else if ((T) < 7) {                                                      \
      gllA(((T)+2)%3, (T)+2, chunk);                                           \
    }                                                                          \
    {                                                                          \
      const int KH = (T)/3, KW = (T)%3;                                        \
      int pp = r6 + wn + KH; if (pp >= 6) pp -= 6;                             \
      const char* bb = ldsb + (pp << 12);                                      \
      bf16x8 af[4], bfr[4];                                                    \
      _Pragma("unroll")                                                        \
      for (int mt = 0; mt < 4; ++mt)                                           \
        af[mt] = __builtin_bit_cast(bf16x8,                                    \
            *reinterpret_cast<const uint4*>(ldsb + 24576 + ((T)%3)*8192 + pa_off[mt])); \
      _Pragma("unroll")                                                        \
      for (int nt = 0; nt < 4; ++nt)                                           \
        bfr[nt] = __builtin_bit_cast(bf16x8,                                   \
            *reinterpret_cast<const uint4*>(bb + b_off[KW] + nt*1024));        \
      if (KW == 0) bfr[0] = m0  ? z8 : bfr[0];                                 \
      if (KW == 2) bfr[3] = m63 ? z8 : bfr[3];                                 \
      __builtin_amdgcn_s_setprio(1);                                           \
      _Pragma("unroll")                                                        \
      for (int mt = 0; mt < 4; ++mt)                                           \
        _Pragma("unroll")                                                      \
        for (int nt = 0; nt < 4; ++nt)                                         \
          acc[mt][nt] = __builtin_amdgcn_mfma_f32_16x16x32_bf16(af[mt], bfr[nt], acc[mt][nt], 0, 0, 0); \
      __builtin_amdgcn_s_setprio(0);                                           \
    }                                                                          \
  }

  // --- prologue: chunk-0 B planes (phys = l), A taps 0,1 ---
  gload_lds16(pB0, ldsb + 0*4096 + wave*1024);
  gload_lds16(pB1, ldsb + 1*4096 + wave*1024);
  gload_lds16(pB2, ldsb + 2*4096 + wave*1024);
  gload_lds16(pB3, ldsb + 3*4096 + wave*1024);
  pB0 += 64; pB1 += 64; pB2 += 64; pB3 += 64;   // advance to chunk-1 ci0
  gllA(0, 0, 0);
  gllA(1, 1, 0);

  int r6 = 0;   // phys base of current chunk's planes: (4*chunk) mod 6

  #pragma unroll 1
  for (int chunk = 0; chunk < 15; ++chunk) {
    const int w6 = (r6 + 4 >= 6) ? (r6 - 2) : (r6 + 4);   // phys base of chunk+1
    TAP(0,2,1) TAP(1,4,1) TAP(2,4,1)
    TAP(3,2,1) TAP(4,3,1) TAP(5,3,1)
    TAP(6,2,1) TAP(7,3,1) TAP(8,3,1)
    pB0 += 64; pB1 += 64; pB2 += 64; pB3 += 64;
    r6 = w6;
  }
  { // tail: chunk 15 (no B prefetch, A prefetch only within chunk)
    const int chunk = 15;
    const int w6 = 0; (void)w6;
    TAP(0,2,0) TAP(1,2,0) TAP(2,2,0)
    TAP(3,2,0) TAP(4,2,0) TAP(5,2,0)
    TAP(6,2,0) TAP(7,2,0) TAP(8,0,0)
  }
#undef TAP
#undef GLB

  // epilogue: C/D layout col=lane&15 (pixel), row=quad*4+reg (co); apply demod here
  #pragma unroll
  for (int mt = 0; mt < 4; ++mt) {
    int co = co0 + wm*64 + mt*16 + quad*4;
    float dvr[4];
    #pragma unroll
    for (int r = 0; r < 4; ++r) dvr[r] = D[b*COUT + co + r];
    #pragma unroll
    for (int nt = 0; nt < 4; ++nt) {
      int px = pt*128 + wn*64 + nt*16 + l15;
      float* op = out + ((size_t)(b*COUT + co))*HW + px;
      #pragma unroll
      for (int r = 0; r < 4; ++r) op[r*HW] = acc[mt][nt][r] * dvr[r];
    }
  }
}

extern "C" void kernel_launch(void* const* d_in, const int* in_sizes, int n_in,
                              void* d_out, int out_size, void* d_ws, size_t ws_size,
                              hipStream_t stream) {
  const float* input  = (const float*)d_in[0];
  const float* style  = (const float*)d_in[1];
  const float* weight = (const float*)d_in[2];
  const float* mod_w  = (const float*)d_in[3];
  const float* mod_b  = (const float*)d_in[4];
  float* out = (float*)d_out;

  char* ws = (char*)d_ws;
  float* S = (float*)ws;                                            //    32 KB
  float* D = (float*)(ws + 32768);                                  //    32 KB
  float* wsq = (float*)(ws + 65536);                                //     1 MB
  unsigned short* wpack = (unsigned short*)(ws + 1114112);          //  4.72 MB (swizzled)
  char* zbuf = ws + 5832704;                                        //     4 KB zeros
  unsigned short* xmod  = (unsigned short*)(ws + 5836800);          // 67.1 MB
  // total ws need: 72,945,664 bytes

  k_style<<<BATCH, 256, 0, stream>>>(style, mod_w, mod_b, S);
  {
    dim3 g(CIN/64, HDIM, BATCH);
    k_xmod<<<g, 256, 0, stream>>>(input, S, xmod);
  }
  k_wsq_pack<<<COUT/4, 256, 0, stream>>>(weight, wsq, wpack, (uint4*)zbuf);
  k_demod<<<(BATCH*COUT)/4, 256, 0, stream>>>(S, wsq, D);

  dim3 grid(HW/128, COUT/128, BATCH);
  k_conv<<<grid, 256, 0, stream>>>(xmod, wpack, D, zbuf, out);
}